// Round 14
// baseline (136.380 us; speedup 1.0000x reference)
//
#include <hip/hip_runtime.h>
#include <cstdint>
#include <cstddef>

typedef __attribute__((ext_vector_type(8))) short short8;
typedef __attribute__((ext_vector_type(4))) float f32x4;
typedef __attribute__((ext_vector_type(2))) float f32x2;

#define MFMA16(a,b,c) __builtin_amdgcn_mfma_f32_16x16x32_bf16((a),(b),(c),0,0,0)
// LDS-only barrier: deliberately NO vmcnt drain (stores stay in flight)
#define BAR() asm volatile("s_waitcnt lgkmcnt(0)\n\ts_barrier" ::: "memory")

static __device__ __forceinline__ unsigned short f2bf(float f) {
  union { float f; unsigned u; } v; v.f = f;
  unsigned r = v.u + 0x7fffu + ((v.u >> 16) & 1u);
  return (unsigned short)(r >> 16);
}
static __device__ __forceinline__ float bf2f(unsigned short h) {
  union { unsigned u; float f; } v; v.u = ((unsigned)h) << 16;
  return v.f;
}

// ---------------- K0: weights f32 -> bf16 ----------------
__global__ __launch_bounds__(256) void k_wcvt(const float* __restrict__ w_val,
                                              const float* __restrict__ w_red,
                                              unsigned short* __restrict__ wv,
                                              unsigned short* __restrict__ wr) {
  int i = blockIdx.x * 256 + threadIdx.x;
  if (i < 65536) wv[i] = f2bf(w_val[i]);
  int j = i - 65536;
  if (j >= 0 && j < 8192) wr[j] = f2bf(w_red[j]);
}

// ---------------- K1: fused transpose + A/sq + val (p-tile 32, 2 WG/CU) ----------------
__global__ __launch_bounds__(512) void k_prep(const float* __restrict__ feat,
                                              const unsigned short* __restrict__ wv,
                                              const unsigned short* __restrict__ wr,
                                              const float* __restrict__ b_red,
                                              const float* __restrict__ b_val,
                                              unsigned short* __restrict__ A,
                                              float* __restrict__ sq,
                                              unsigned short* __restrict__ val) {
  __shared__ unsigned short smT[32][264];
  __shared__ float sqp[2][32];
  const int t = threadIdx.x, w = t >> 6, lane = t & 63, a = lane & 15, g = lane >> 4;
  const int b = blockIdx.y, p0 = blockIdx.x * 32;
  const float* fb = feat + (size_t)b * 256 * 4096;
  {
    const int p = t & 31, cg = t >> 5;
#pragma unroll
    for (int it = 0; it < 4; ++it) {
      int c0 = cg * 4 + it * 64;
      const float* src = fb + (size_t)c0 * 4096 + p0 + p;
      unsigned short u0 = f2bf(src[0]);
      unsigned short u1 = f2bf(src[4096]);
      unsigned short u2 = f2bf(src[8192]);
      unsigned short u3 = f2bf(src[12288]);
      uint2 pk;
      pk.x = u0 | ((unsigned)u1 << 16);
      pk.y = u2 | ((unsigned)u3 << 16);
      *(uint2*)&smT[p][c0] = pk;
    }
  }
  __syncthreads();

  f32x4 accv[2][2] = {};
  const int rs = w & 1, rms = (w >> 1) & 1;
  f32x4 accr = {0, 0, 0, 0};
#pragma unroll
  for (int kk = 0; kk < 8; ++kk) {
    short8 bfr[2];
#pragma unroll
    for (int ms = 0; ms < 2; ++ms)
      bfr[ms] = *(const short8*)&smT[ms * 16 + a][kk * 32 + g * 8];
#pragma unroll
    for (int s = 0; s < 2; ++s) {
      short8 af = *(const short8*)&wv[(w * 32 + s * 16 + a) * 256 + kk * 32 + g * 8];
#pragma unroll
      for (int ms = 0; ms < 2; ++ms)
        accv[s][ms] = MFMA16(af, bfr[ms], accv[s][ms]);
    }
    if (w < 4) {
      short8 wrf = *(const short8*)&wr[(rs * 16 + a) * 256 + kk * 32 + g * 8];
      accr = MFMA16(bfr[rms], wrf, accr);
    }
  }
#pragma unroll
  for (int s = 0; s < 2; ++s) {
    f32x4 bv = *(const f32x4*)&b_val[w * 32 + s * 16 + g * 4];
#pragma unroll
    for (int ms = 0; ms < 2; ++ms) {
#pragma unroll
      for (int r = 0; r < 4; ++r) {
        float v = accv[s][ms][r] + bv[r];
        v = v > 0.f ? v : 0.f;
        int o = w * 32 + s * 16 + g * 4 + r;
        val[((size_t)(b * 256 + o)) * 4096 + p0 + ms * 16 + a] = f2bf(v);
      }
    }
  }
  if (w < 4) {
    float bias = b_red[rs * 16 + a];
    float rsum[4];
    unsigned short* Ab = A + ((size_t)b * 4096 + p0 + rms * 16) * 32;
#pragma unroll
    for (int r = 0; r < 4; ++r) {
      float v = accr[r] + bias;
      v = v > 0.f ? v : 0.f;
      unsigned short h = f2bf(v);
      Ab[(g * 4 + r) * 32 + rs * 16 + a] = h;
      float vb = bf2f(h);
      rsum[r] = vb * vb;
    }
#pragma unroll
    for (int off = 1; off < 16; off <<= 1) {
#pragma unroll
      for (int r = 0; r < 4; ++r) rsum[r] += __shfl_xor(rsum[r], off, 64);
    }
    if (a == 0) {
#pragma unroll
      for (int r = 0; r < 4; ++r) sqp[rs][rms * 16 + g * 4 + r] = rsum[r];
    }
  }
  __syncthreads();
  if (t < 32) sq[(size_t)b * 4096 + p0 + t] = sqp[0][t] + sqp[1][t];
}

// mask subtile: S = A_n . A_m^T, mask = sigmoid(exp(-D)) packed to 2x2 bf16
static __device__ __forceinline__ uint2 mask_tile(const unsigned short* __restrict__ Ab,
                                                  const float* __restrict__ sqb,
                                                  int nbase, int ns, int a, int g,
                                                  short8 am, float sqm) {
  const f32x4 zero = {0, 0, 0, 0};
  short8 an = *(const short8*)&Ab[(size_t)(nbase + ns * 16 + a) * 32 + g * 8];
  f32x4 sqn = *(const f32x4*)&sqb[nbase + ns * 16 + g * 4];
  f32x4 sfr = MFMA16(an, am, zero);
  unsigned short h[4];
#pragma unroll
  for (int r = 0; r < 4; ++r) {
    float u = __expf(fmaf(2.f, sfr[r], -(sqn[r] + sqm)));  // exp(-D) in (0,1]
    float u2 = u * u;
    float pa = fmaf(u2, 2.0833333e-3f, -2.0833333e-2f);
    float pb = fmaf(u2, pa, 0.25f);
    h[r] = f2bf(fmaf(u, pb, 0.5f));  // sigmoid poly, |err|<=2.2e-4
  }
  uint2 pk;
  pk.x = h[0] | ((unsigned)h[1] << 16);
  pk.y = h[2] | ((unsigned)h[3] << 16);
  return pk;
}

// ---------------- K2: fused mask + (val @ mask) + residual, ROLE-SPECIALIZED ----------------
// r9 champion + DRAM-write-locality changes:
//  (1) per-WG n-phase stagger (phase = (swz&15)*4, logical tile tau -> cols
//      ((phase+tau)&63)*64) so concurrent WGs hit DIFFERENT channel offsets;
//  (2) 8-slot LDS ring; store waves fire every 4th step and write each row's
//      1KB as ONE full-wave nt dwordx4 (4 consolidated tiles, wrap-free since
//      phase%4==0) -> 4x fewer DRAM row activations, 4x longer bursts.
//  waves 0-7  GEMM : consume slot tt&7 (16 MFMA/step).
//  waves 8-11 S    : produce tile tt+1 -> slot (tt+1)&7.
//  waves 12-15 STORE: at tt%4==3, rows [16sw,16sw+16): 1KB nt burst per row.
// One lgkm-only barrier per step; no vmcnt drain anywhere in the loop.
__global__ __launch_bounds__(1024) void k_fused(const unsigned short* __restrict__ A,
                                                const float* __restrict__ sq,
                                                const unsigned short* __restrict__ val,
                                                const float* __restrict__ feat,
                                                float* __restrict__ dout) {
  __shared__ unsigned short ldsT[8][64][72];  // bf16 [m][n] ring, 9 x 16B row stride
  const int t = threadIdx.x, w = t >> 6, lane = t & 63, a = lane & 15, g = lane >> 4;
  // bijective XCD swizzle: 32 contiguous WGs per XCD; XCD pair {2b,2b+1} <-> batch b
  const int lin = blockIdx.x + (blockIdx.y << 6);
  const int swz = (lin & 7) * 32 + (lin >> 3);
  const int b = swz >> 6, m0 = (swz & 63) * 64;
  const int phase = (swz & 15) << 2;  // 0,4,..,60 — multiple of 4 (wrap-free groups)
  const unsigned short* Ab = A + (size_t)b * 4096 * 32;
  const float* sqb = sq + (size_t)b * 4096;
  float* maskout = dout + 4194304 + (size_t)b * 16777216;

  if (w < 8) {
    // ================= GEMM waves: c rows [32w, 32w+32) =================
    const unsigned short* vrow = val + ((size_t)(b * 256 + w * 32)) * 4096;
    f32x4 acc[2][4] = {};
    BAR();
    for (int tt = 0; tt < 64; ++tt) {
      const int n0 = ((phase + tt) & 63) << 6, sl = tt & 7;
      short8 vf[2][2];
#pragma unroll
      for (int cs = 0; cs < 2; ++cs)
#pragma unroll
        for (int ks = 0; ks < 2; ++ks)
          vf[cs][ks] = *(const short8*)&vrow[(size_t)(cs * 16 + a) * 4096 + n0 + ks * 32 + g * 8];
      short8 bfr[2][4];
#pragma unroll
      for (int ks = 0; ks < 2; ++ks)
#pragma unroll
        for (int ms = 0; ms < 4; ++ms)
          bfr[ks][ms] = *(const short8*)&ldsT[sl][ms * 16 + a][ks * 32 + g * 8];
#pragma unroll
      for (int ks = 0; ks < 2; ++ks)
#pragma unroll
        for (int cs = 0; cs < 2; ++cs)
#pragma unroll
          for (int ms = 0; ms < 4; ++ms)
            acc[cs][ms] = MFMA16(vf[cs][ks], bfr[ks][ms], acc[cs][ms]);
      BAR();
    }
    // epilogue: out = acc + features
    const float* fb = feat + (size_t)b * 256 * 4096;
    float* ob = dout + (size_t)b * 256 * 4096;
#pragma unroll
    for (int cs = 0; cs < 2; ++cs) {
#pragma unroll
      for (int ms = 0; ms < 4; ++ms) {
#pragma unroll
        for (int r = 0; r < 4; ++r) {
          int c = w * 32 + cs * 16 + g * 4 + r;
          int m = m0 + ms * 16 + a;
          size_t idx = (size_t)c * 4096 + m;
          float fv = __builtin_nontemporal_load(&fb[idx]);
          __builtin_nontemporal_store(acc[cs][ms][r] + fv, &ob[idx]);
        }
      }
    }
  } else if (w < 12) {
    // ================= S waves: m-rows [16(w-8), 16(w-8)+16) =================
    const int msub = w - 8;
    const int mrow = m0 + msub * 16 + a;
    const short8 am = *(const short8*)&Ab[(size_t)mrow * 32 + g * 8];
    const float sqm = sqb[mrow];
    // prologue: tile 0 -> slot 0
#pragma unroll
    for (int ns = 0; ns < 4; ++ns) {
      uint2 pk = mask_tile(Ab, sqb, phase << 6, ns, a, g, am, sqm);
      *(uint2*)&ldsT[0][msub * 16 + a][ns * 16 + g * 4] = pk;
    }
    BAR();
    for (int tt = 0; tt < 64; ++tt) {
      if (tt < 63) {
        const int nn = ((phase + tt + 1) & 63) << 6, sl = (tt + 1) & 7;
#pragma unroll
        for (int ns = 0; ns < 4; ++ns) {
          uint2 pk = mask_tile(Ab, sqb, nn, ns, a, g, am, sqm);
          *(uint2*)&ldsT[sl][msub * 16 + a][ns * 16 + g * 4] = pk;
        }
      }
      BAR();
    }
  } else {
    // ================= STORE waves: m-rows [16(w-12), 16(w-12)+16) =================
    const int sw = w - 12;
    const int q = lane >> 4, cl = lane & 15;  // lane covers float [lane*4, lane*4+4)
    const unsigned short* ldsBase = &ldsT[0][0][0];
    BAR();
    for (int tt = 0; tt < 64; ++tt) {
      if ((tt & 3) == 3) {
        const int tau0 = tt - 3;                       // first tile of group
        const int cb = ((phase + tau0) & 63) << 6;     // column base (wrap-free x4)
        const int sl = (tau0 + q) & 7;                 // per-lane-quarter slot
#pragma unroll
        for (int j = 0; j < 16; ++j) {
          const int row = sw * 16 + j;
          uint2 u = *(const uint2*)(ldsBase + (size_t)sl * 4608 + row * 72 + cl * 4);
          f32x4 v;
          v[0] = bf2f((unsigned short)(u.x & 0xffff));
          v[1] = bf2f((unsigned short)(u.x >> 16));
          v[2] = bf2f((unsigned short)(u.y & 0xffff));
          v[3] = bf2f((unsigned short)(u.y >> 16));
          // one full-wave 1KB contiguous nt burst per row
          __builtin_nontemporal_store(v, (f32x4*)&maskout[(size_t)(m0 + row) * 4096 + cb + lane * 4]);
        }
      }
      BAR();
    }
  }
}

extern "C" void kernel_launch(void* const* d_in, const int* in_sizes, int n_in,
                              void* d_out, int out_size, void* d_ws, size_t ws_size,
                              hipStream_t stream) {
  const float* feat  = (const float*)d_in[0];
  const float* w_red = (const float*)d_in[1];
  const float* b_red = (const float*)d_in[2];
  const float* w_val = (const float*)d_in[3];
  const float* b_val = (const float*)d_in[4];
  float* out = (float*)d_out;
  char* ws = (char*)d_ws;
  unsigned short* A   = (unsigned short*)ws;               // 1,048,576 B
  float*          sq  = (float*)        (ws + 1048576);    //    65,536 B
  unsigned short* wv  = (unsigned short*)(ws + 1114112);   //   131,072 B
  unsigned short* wr  = (unsigned short*)(ws + 1245184);   //    16,384 B
  unsigned short* val = (unsigned short*)(ws + 1261568);   // 8,388,608 B

  k_wcvt<<<dim3(288), 256, 0, stream>>>(w_val, w_red, wv, wr);
  k_prep<<<dim3(128, 4), 512, 0, stream>>>(feat, wv, wr, b_red, b_val, A, sq, val);
  k_fused<<<dim3(64, 4), 1024, 0, stream>>>(A, sq, val, feat, out);
}

// Round 15
// 120.686 us; speedup vs baseline: 1.1300x; 1.1300x over previous
//
#include <hip/hip_runtime.h>
#include <cstdint>
#include <cstddef>

typedef __attribute__((ext_vector_type(8))) short short8;
typedef __attribute__((ext_vector_type(4))) float f32x4;
typedef __attribute__((ext_vector_type(2))) float f32x2;

#define MFMA16(a,b,c) __builtin_amdgcn_mfma_f32_16x16x32_bf16((a),(b),(c),0,0,0)
// LDS-only barrier: deliberately NO vmcnt drain (stores stay in flight)
#define BAR() asm volatile("s_waitcnt lgkmcnt(0)\n\ts_barrier" ::: "memory")

static __device__ __forceinline__ unsigned short f2bf(float f) {
  union { float f; unsigned u; } v; v.f = f;
  unsigned r = v.u + 0x7fffu + ((v.u >> 16) & 1u);
  return (unsigned short)(r >> 16);
}
static __device__ __forceinline__ float bf2f(unsigned short h) {
  union { unsigned u; float f; } v; v.u = ((unsigned)h) << 16;
  return v.f;
}

// ---------------- K0: weights f32 -> bf16 ----------------
__global__ __launch_bounds__(256) void k_wcvt(const float* __restrict__ w_val,
                                              const float* __restrict__ w_red,
                                              unsigned short* __restrict__ wv,
                                              unsigned short* __restrict__ wr) {
  int i = blockIdx.x * 256 + threadIdx.x;
  if (i < 65536) wv[i] = f2bf(w_val[i]);
  int j = i - 65536;
  if (j >= 0 && j < 8192) wr[j] = f2bf(w_red[j]);
}

// ---------------- K1: fused transpose + A/sq + val (p-tile 32, 2 WG/CU) ----------------
__global__ __launch_bounds__(512) void k_prep(const float* __restrict__ feat,
                                              const unsigned short* __restrict__ wv,
                                              const unsigned short* __restrict__ wr,
                                              const float* __restrict__ b_red,
                                              const float* __restrict__ b_val,
                                              unsigned short* __restrict__ A,
                                              float* __restrict__ sq,
                                              unsigned short* __restrict__ val) {
  __shared__ unsigned short smT[32][264];
  __shared__ float sqp[2][32];
  const int t = threadIdx.x, w = t >> 6, lane = t & 63, a = lane & 15, g = lane >> 4;
  const int b = blockIdx.y, p0 = blockIdx.x * 32;
  const float* fb = feat + (size_t)b * 256 * 4096;
  {
    const int p = t & 31, cg = t >> 5;
#pragma unroll
    for (int it = 0; it < 4; ++it) {
      int c0 = cg * 4 + it * 64;
      const float* src = fb + (size_t)c0 * 4096 + p0 + p;
      unsigned short u0 = f2bf(src[0]);
      unsigned short u1 = f2bf(src[4096]);
      unsigned short u2 = f2bf(src[8192]);
      unsigned short u3 = f2bf(src[12288]);
      uint2 pk;
      pk.x = u0 | ((unsigned)u1 << 16);
      pk.y = u2 | ((unsigned)u3 << 16);
      *(uint2*)&smT[p][c0] = pk;
    }
  }
  __syncthreads();

  f32x4 accv[2][2] = {};
  const int rs = w & 1, rms = (w >> 1) & 1;
  f32x4 accr = {0, 0, 0, 0};
#pragma unroll
  for (int kk = 0; kk < 8; ++kk) {
    short8 bfr[2];
#pragma unroll
    for (int ms = 0; ms < 2; ++ms)
      bfr[ms] = *(const short8*)&smT[ms * 16 + a][kk * 32 + g * 8];
#pragma unroll
    for (int s = 0; s < 2; ++s) {
      short8 af = *(const short8*)&wv[(w * 32 + s * 16 + a) * 256 + kk * 32 + g * 8];
#pragma unroll
      for (int ms = 0; ms < 2; ++ms)
        accv[s][ms] = MFMA16(af, bfr[ms], accv[s][ms]);
    }
    if (w < 4) {
      short8 wrf = *(const short8*)&wr[(rs * 16 + a) * 256 + kk * 32 + g * 8];
      accr = MFMA16(bfr[rms], wrf, accr);
    }
  }
#pragma unroll
  for (int s = 0; s < 2; ++s) {
    f32x4 bv = *(const f32x4*)&b_val[w * 32 + s * 16 + g * 4];
#pragma unroll
    for (int ms = 0; ms < 2; ++ms) {
#pragma unroll
      for (int r = 0; r < 4; ++r) {
        float v = accv[s][ms][r] + bv[r];
        v = v > 0.f ? v : 0.f;
        int o = w * 32 + s * 16 + g * 4 + r;
        val[((size_t)(b * 256 + o)) * 4096 + p0 + ms * 16 + a] = f2bf(v);
      }
    }
  }
  if (w < 4) {
    float bias = b_red[rs * 16 + a];
    float rsum[4];
    unsigned short* Ab = A + ((size_t)b * 4096 + p0 + rms * 16) * 32;
#pragma unroll
    for (int r = 0; r < 4; ++r) {
      float v = accr[r] + bias;
      v = v > 0.f ? v : 0.f;
      unsigned short h = f2bf(v);
      Ab[(g * 4 + r) * 32 + rs * 16 + a] = h;
      float vb = bf2f(h);
      rsum[r] = vb * vb;
    }
#pragma unroll
    for (int off = 1; off < 16; off <<= 1) {
#pragma unroll
      for (int r = 0; r < 4; ++r) rsum[r] += __shfl_xor(rsum[r], off, 64);
    }
    if (a == 0) {
#pragma unroll
      for (int r = 0; r < 4; ++r) sqp[rs][rms * 16 + g * 4 + r] = rsum[r];
    }
  }
  __syncthreads();
  if (t < 32) sq[(size_t)b * 4096 + p0 + t] = sqp[0][t] + sqp[1][t];
}

// mask subtile: S = A_n . A_m^T, mask = sigmoid(exp(-D)) packed to 2x2 bf16
static __device__ __forceinline__ uint2 mask_tile(const unsigned short* __restrict__ Ab,
                                                  const float* __restrict__ sqb,
                                                  int nbase, int ns, int a, int g,
                                                  short8 am, float sqm) {
  const f32x4 zero = {0, 0, 0, 0};
  short8 an = *(const short8*)&Ab[(size_t)(nbase + ns * 16 + a) * 32 + g * 8];
  f32x4 sqn = *(const f32x4*)&sqb[nbase + ns * 16 + g * 4];
  f32x4 sfr = MFMA16(an, am, zero);
  unsigned short h[4];
#pragma unroll
  for (int r = 0; r < 4; ++r) {
    float u = __expf(fmaf(2.f, sfr[r], -(sqn[r] + sqm)));  // exp(-D) in (0,1]
    float u2 = u * u;
    float pa = fmaf(u2, 2.0833333e-3f, -2.0833333e-2f);
    float pb = fmaf(u2, pa, 0.25f);
    h[r] = f2bf(fmaf(u, pb, 0.5f));  // sigmoid poly, |err|<=2.2e-4
  }
  uint2 pk;
  pk.x = h[0] | ((unsigned)h[1] << 16);
  pk.y = h[2] | ((unsigned)h[3] << 16);
  return pk;
}

// ---------------- K2: fused mask + (val @ mask) + residual, ROLE-SPECIALIZED ----------------
// r9 (127 us) champion + ONE variable: the GEMM-wave EPILOGUE uses plain cached
// loads/stores instead of nontemporal. Rationale: at epilogue time the loop is
// done, so L2 write-allocate pollution is harmless (val is dead), and the
// cached streaming path runs at fill-kernel rate (~6.7 TB/s) vs nt ~2.9.
// In-loop mask stores stay nt (r10 proved cached mask stores thrash val).
//  waves 0-7  GEMM : val loads + ldsT reads + 16 MFMA/step.
//  waves 8-11 S    : A/sq loads + 4 MFMA + exp -> bf16 tile tt+1 into ldsT.
//  waves 12-15 STORE: ldsT -> widen -> nt dwordx2; vmcnt never waited on.
__global__ __launch_bounds__(1024) void k_fused(const unsigned short* __restrict__ A,
                                                const float* __restrict__ sq,
                                                const unsigned short* __restrict__ val,
                                                const float* __restrict__ feat,
                                                float* __restrict__ dout) {
  __shared__ unsigned short ldsT[2][64][72];  // bf16 [m][n] tiles, 9 x 16B row stride
  const int t = threadIdx.x, w = t >> 6, lane = t & 63, a = lane & 15, g = lane >> 4;
  // bijective XCD swizzle: 32 contiguous WGs per XCD; XCD pair {2b,2b+1} <-> batch b
  const int lin = blockIdx.x + (blockIdx.y << 6);
  const int swz = (lin & 7) * 32 + (lin >> 3);
  const int b = swz >> 6, m0 = (swz & 63) * 64;
  const unsigned short* Ab = A + (size_t)b * 4096 * 32;
  const float* sqb = sq + (size_t)b * 4096;
  float* maskout = dout + 4194304 + (size_t)b * 16777216;

  if (w < 8) {
    // ================= GEMM waves: c rows [32w, 32w+32) =================
    const unsigned short* vrow = val + ((size_t)(b * 256 + w * 32)) * 4096;
    f32x4 acc[2][4] = {};
    BAR();
    for (int tt = 0; tt < 64; ++tt) {
      const int n0 = tt * 64, buf = tt & 1;
      short8 vf[2][2];
#pragma unroll
      for (int cs = 0; cs < 2; ++cs)
#pragma unroll
        for (int ks = 0; ks < 2; ++ks)
          vf[cs][ks] = *(const short8*)&vrow[(size_t)(cs * 16 + a) * 4096 + n0 + ks * 32 + g * 8];
      short8 bfr[2][4];
#pragma unroll
      for (int ks = 0; ks < 2; ++ks)
#pragma unroll
        for (int ms = 0; ms < 4; ++ms)
          bfr[ks][ms] = *(const short8*)&ldsT[buf][ms * 16 + a][ks * 32 + g * 8];
#pragma unroll
      for (int ks = 0; ks < 2; ++ks)
#pragma unroll
        for (int cs = 0; cs < 2; ++cs)
#pragma unroll
          for (int ms = 0; ms < 4; ++ms)
            acc[cs][ms] = MFMA16(vf[cs][ks], bfr[ks][ms], acc[cs][ms]);
      BAR();
    }
    // epilogue: out = acc + features — CACHED path (L2 streams at fill rate;
    // pollution is harmless now that the loop's val reads are done)
    const float* fb = feat + (size_t)b * 256 * 4096;
    float* ob = dout + (size_t)b * 256 * 4096;
#pragma unroll
    for (int cs = 0; cs < 2; ++cs) {
#pragma unroll
      for (int ms = 0; ms < 4; ++ms) {
#pragma unroll
        for (int r = 0; r < 4; ++r) {
          int c = w * 32 + cs * 16 + g * 4 + r;
          int m = m0 + ms * 16 + a;
          size_t idx = (size_t)c * 4096 + m;
          ob[idx] = acc[cs][ms][r] + fb[idx];
        }
      }
    }
  } else if (w < 12) {
    // ================= S waves: m-rows [16(w-8), 16(w-8)+16) =================
    const int msub = w - 8;
    const int mrow = m0 + msub * 16 + a;
    const short8 am = *(const short8*)&Ab[(size_t)mrow * 32 + g * 8];
    const float sqm = sqb[mrow];
    // prologue: tile 0 -> ldsT[0]
#pragma unroll
    for (int ns = 0; ns < 4; ++ns) {
      uint2 pk = mask_tile(Ab, sqb, 0, ns, a, g, am, sqm);
      *(uint2*)&ldsT[0][msub * 16 + a][ns * 16 + g * 4] = pk;
    }
    BAR();
    for (int tt = 0; tt < 64; ++tt) {
      if (tt < 63) {
        const int nn = (tt + 1) * 64, tb = (tt + 1) & 1;
#pragma unroll
        for (int ns = 0; ns < 4; ++ns) {
          uint2 pk = mask_tile(Ab, sqb, nn, ns, a, g, am, sqm);
          *(uint2*)&ldsT[tb][msub * 16 + a][ns * 16 + g * 4] = pk;
        }
      }
      BAR();
    }
  } else {
    // ================= STORE waves: m-rows [16(w-12), 16(w-12)+16) =================
    const int sw = w - 12;
    const int rr = lane >> 5, cc = (lane & 31) * 2;
    BAR();
    for (int tt = 0; tt < 64; ++tt) {
      const int n0 = tt * 64, buf = tt & 1;
#pragma unroll
      for (int j = 0; j < 8; ++j) {
        const int row = sw * 16 + j * 2 + rr;
        unsigned u = *(const unsigned*)&ldsT[buf][row][cc];
        f32x2 v;
        v[0] = bf2f((unsigned short)(u & 0xffff));
        v[1] = bf2f((unsigned short)(u >> 16));
        __builtin_nontemporal_store(v, (f32x2*)&maskout[(size_t)(m0 + row) * 4096 + n0 + cc]);
      }
      BAR();
    }
  }
}

extern "C" void kernel_launch(void* const* d_in, const int* in_sizes, int n_in,
                              void* d_out, int out_size, void* d_ws, size_t ws_size,
                              hipStream_t stream) {
  const float* feat  = (const float*)d_in[0];
  const float* w_red = (const float*)d_in[1];
  const float* b_red = (const float*)d_in[2];
  const float* w_val = (const float*)d_in[3];
  const float* b_val = (const float*)d_in[4];
  float* out = (float*)d_out;
  char* ws = (char*)d_ws;
  unsigned short* A   = (unsigned short*)ws;               // 1,048,576 B
  float*          sq  = (float*)        (ws + 1048576);    //    65,536 B
  unsigned short* wv  = (unsigned short*)(ws + 1114112);   //   131,072 B
  unsigned short* wr  = (unsigned short*)(ws + 1245184);   //    16,384 B
  unsigned short* val = (unsigned short*)(ws + 1261568);   // 8,388,608 B

  k_wcvt<<<dim3(288), 256, 0, stream>>>(w_val, w_red, wv, wr);
  k_prep<<<dim3(128, 4), 512, 0, stream>>>(feat, wv, wr, b_red, b_val, A, sq, val);
  k_fused<<<dim3(64, 4), 1024, 0, stream>>>(A, sq, val, feat, out);
}

// Round 16
// 120.536 us; speedup vs baseline: 1.1314x; 1.0012x over previous
//
#include <hip/hip_runtime.h>
#include <cstdint>
#include <cstddef>

typedef __attribute__((ext_vector_type(8))) short short8;
typedef __attribute__((ext_vector_type(4))) float f32x4;
typedef __attribute__((ext_vector_type(2))) float f32x2;

#define MFMA16(a,b,c) __builtin_amdgcn_mfma_f32_16x16x32_bf16((a),(b),(c),0,0,0)
// LDS-only barrier: deliberately NO vmcnt drain (stores stay in flight)
#define BAR() asm volatile("s_waitcnt lgkmcnt(0)\n\ts_barrier" ::: "memory")

static __device__ __forceinline__ unsigned short f2bf(float f) {
  union { float f; unsigned u; } v; v.f = f;
  unsigned r = v.u + 0x7fffu + ((v.u >> 16) & 1u);
  return (unsigned short)(r >> 16);
}
static __device__ __forceinline__ float bf2f(unsigned short h) {
  union { unsigned u; float f; } v; v.u = ((unsigned)h) << 16;
  return v.f;
}

// ---------------- K0: weights f32 -> bf16 ----------------
__global__ __launch_bounds__(256) void k_wcvt(const float* __restrict__ w_val,
                                              const float* __restrict__ w_red,
                                              unsigned short* __restrict__ wv,
                                              unsigned short* __restrict__ wr) {
  int i = blockIdx.x * 256 + threadIdx.x;
  if (i < 65536) wv[i] = f2bf(w_val[i]);
  int j = i - 65536;
  if (j >= 0 && j < 8192) wr[j] = f2bf(w_red[j]);
}

// ---------------- K1: fused transpose + A/sq + val (p-tile 32, 2 WG/CU) ----------------
// r15 + ONE change: stage loop reads float4 (16B/lane, G13 sweet spot) instead
// of 4 strided scalar dwords; LDS transpose-write becomes 4 ds_write_b16
// (minor bank aliasing, one-time cost) in exchange for 4x fewer global load
// instructions and deeper load ILP.
__global__ __launch_bounds__(512) void k_prep(const float* __restrict__ feat,
                                              const unsigned short* __restrict__ wv,
                                              const unsigned short* __restrict__ wr,
                                              const float* __restrict__ b_red,
                                              const float* __restrict__ b_val,
                                              unsigned short* __restrict__ A,
                                              float* __restrict__ sq,
                                              unsigned short* __restrict__ val) {
  __shared__ unsigned short smT[32][264];
  __shared__ float sqp[2][32];
  const int t = threadIdx.x, w = t >> 6, lane = t & 63, a = lane & 15, g = lane >> 4;
  const int b = blockIdx.y, p0 = blockIdx.x * 32;
  const float* fb = feat + (size_t)b * 256 * 4096;
  {
    // vectorized stage: thread covers 4 consecutive p of one c-row per pass
    const int pq = (t & 7) * 4;   // 8 lanes x 4p = 32 p
    const int crow = t >> 3;      // 64 c-rows per pass
    float4 fv[4];
#pragma unroll
    for (int pass = 0; pass < 4; ++pass) {
      int c = crow + pass * 64;
      fv[pass] = *(const float4*)&fb[(size_t)c * 4096 + p0 + pq];
    }
#pragma unroll
    for (int pass = 0; pass < 4; ++pass) {
      int c = crow + pass * 64;
      smT[pq + 0][c] = f2bf(fv[pass].x);
      smT[pq + 1][c] = f2bf(fv[pass].y);
      smT[pq + 2][c] = f2bf(fv[pass].z);
      smT[pq + 3][c] = f2bf(fv[pass].w);
    }
  }
  __syncthreads();

  f32x4 accv[2][2] = {};
  const int rs = w & 1, rms = (w >> 1) & 1;
  f32x4 accr = {0, 0, 0, 0};
#pragma unroll
  for (int kk = 0; kk < 8; ++kk) {
    short8 bfr[2];
#pragma unroll
    for (int ms = 0; ms < 2; ++ms)
      bfr[ms] = *(const short8*)&smT[ms * 16 + a][kk * 32 + g * 8];
#pragma unroll
    for (int s = 0; s < 2; ++s) {
      short8 af = *(const short8*)&wv[(w * 32 + s * 16 + a) * 256 + kk * 32 + g * 8];
#pragma unroll
      for (int ms = 0; ms < 2; ++ms)
        accv[s][ms] = MFMA16(af, bfr[ms], accv[s][ms]);
    }
    if (w < 4) {
      short8 wrf = *(const short8*)&wr[(rs * 16 + a) * 256 + kk * 32 + g * 8];
      accr = MFMA16(bfr[rms], wrf, accr);
    }
  }
#pragma unroll
  for (int s = 0; s < 2; ++s) {
    f32x4 bv = *(const f32x4*)&b_val[w * 32 + s * 16 + g * 4];
#pragma unroll
    for (int ms = 0; ms < 2; ++ms) {
#pragma unroll
      for (int r = 0; r < 4; ++r) {
        float v = accv[s][ms][r] + bv[r];
        v = v > 0.f ? v : 0.f;
        int o = w * 32 + s * 16 + g * 4 + r;
        val[((size_t)(b * 256 + o)) * 4096 + p0 + ms * 16 + a] = f2bf(v);
      }
    }
  }
  if (w < 4) {
    float bias = b_red[rs * 16 + a];
    float rsum[4];
    unsigned short* Ab = A + ((size_t)b * 4096 + p0 + rms * 16) * 32;
#pragma unroll
    for (int r = 0; r < 4; ++r) {
      float v = accr[r] + bias;
      v = v > 0.f ? v : 0.f;
      unsigned short h = f2bf(v);
      Ab[(g * 4 + r) * 32 + rs * 16 + a] = h;
      float vb = bf2f(h);
      rsum[r] = vb * vb;
    }
#pragma unroll
    for (int off = 1; off < 16; off <<= 1) {
#pragma unroll
      for (int r = 0; r < 4; ++r) rsum[r] += __shfl_xor(rsum[r], off, 64);
    }
    if (a == 0) {
#pragma unroll
      for (int r = 0; r < 4; ++r) sqp[rs][rms * 16 + g * 4 + r] = rsum[r];
    }
  }
  __syncthreads();
  if (t < 32) sq[(size_t)b * 4096 + p0 + t] = sqp[0][t] + sqp[1][t];
}

// mask subtile: S = A_n . A_m^T, mask = sigmoid(exp(-D)) packed to 2x2 bf16
static __device__ __forceinline__ uint2 mask_tile(const unsigned short* __restrict__ Ab,
                                                  const float* __restrict__ sqb,
                                                  int nbase, int ns, int a, int g,
                                                  short8 am, float sqm) {
  const f32x4 zero = {0, 0, 0, 0};
  short8 an = *(const short8*)&Ab[(size_t)(nbase + ns * 16 + a) * 32 + g * 8];
  f32x4 sqn = *(const f32x4*)&sqb[nbase + ns * 16 + g * 4];
  f32x4 sfr = MFMA16(an, am, zero);
  unsigned short h[4];
#pragma unroll
  for (int r = 0; r < 4; ++r) {
    float u = __expf(fmaf(2.f, sfr[r], -(sqn[r] + sqm)));  // exp(-D) in (0,1]
    float u2 = u * u;
    float pa = fmaf(u2, 2.0833333e-3f, -2.0833333e-2f);
    float pb = fmaf(u2, pa, 0.25f);
    h[r] = f2bf(fmaf(u, pb, 0.5f));  // sigmoid poly, |err|<=2.2e-4
  }
  uint2 pk;
  pk.x = h[0] | ((unsigned)h[1] << 16);
  pk.y = h[2] | ((unsigned)h[3] << 16);
  return pk;
}

// ---------------- K2: fused mask + (val @ mask) + residual, ROLE-SPECIALIZED ----------------
// r15 champion, unchanged: nt mask stores from dedicated store waves (vmcnt
// never waited on), cached epilogue, lgkm-only barriers.
//  waves 0-7  GEMM : val loads + ldsT reads + 16 MFMA/step.
//  waves 8-11 S    : A/sq loads + 4 MFMA + exp -> bf16 tile tt+1 into ldsT.
//  waves 12-15 STORE: ldsT -> widen -> nt dwordx2.
__global__ __launch_bounds__(1024) void k_fused(const unsigned short* __restrict__ A,
                                                const float* __restrict__ sq,
                                                const unsigned short* __restrict__ val,
                                                const float* __restrict__ feat,
                                                float* __restrict__ dout) {
  __shared__ unsigned short ldsT[2][64][72];  // bf16 [m][n] tiles, 9 x 16B row stride
  const int t = threadIdx.x, w = t >> 6, lane = t & 63, a = lane & 15, g = lane >> 4;
  // bijective XCD swizzle: 32 contiguous WGs per XCD; XCD pair {2b,2b+1} <-> batch b
  const int lin = blockIdx.x + (blockIdx.y << 6);
  const int swz = (lin & 7) * 32 + (lin >> 3);
  const int b = swz >> 6, m0 = (swz & 63) * 64;
  const unsigned short* Ab = A + (size_t)b * 4096 * 32;
  const float* sqb = sq + (size_t)b * 4096;
  float* maskout = dout + 4194304 + (size_t)b * 16777216;

  if (w < 8) {
    // ================= GEMM waves: c rows [32w, 32w+32) =================
    const unsigned short* vrow = val + ((size_t)(b * 256 + w * 32)) * 4096;
    f32x4 acc[2][4] = {};
    BAR();
    for (int tt = 0; tt < 64; ++tt) {
      const int n0 = tt * 64, buf = tt & 1;
      short8 vf[2][2];
#pragma unroll
      for (int cs = 0; cs < 2; ++cs)
#pragma unroll
        for (int ks = 0; ks < 2; ++ks)
          vf[cs][ks] = *(const short8*)&vrow[(size_t)(cs * 16 + a) * 4096 + n0 + ks * 32 + g * 8];
      short8 bfr[2][4];
#pragma unroll
      for (int ks = 0; ks < 2; ++ks)
#pragma unroll
        for (int ms = 0; ms < 4; ++ms)
          bfr[ks][ms] = *(const short8*)&ldsT[buf][ms * 16 + a][ks * 32 + g * 8];
#pragma unroll
      for (int ks = 0; ks < 2; ++ks)
#pragma unroll
        for (int cs = 0; cs < 2; ++cs)
#pragma unroll
          for (int ms = 0; ms < 4; ++ms)
            acc[cs][ms] = MFMA16(vf[cs][ks], bfr[ks][ms], acc[cs][ms]);
      BAR();
    }
    // epilogue: out = acc + features — CACHED path (pollution harmless now)
    const float* fb = feat + (size_t)b * 256 * 4096;
    float* ob = dout + (size_t)b * 256 * 4096;
#pragma unroll
    for (int cs = 0; cs < 2; ++cs) {
#pragma unroll
      for (int ms = 0; ms < 4; ++ms) {
#pragma unroll
        for (int r = 0; r < 4; ++r) {
          int c = w * 32 + cs * 16 + g * 4 + r;
          int m = m0 + ms * 16 + a;
          size_t idx = (size_t)c * 4096 + m;
          ob[idx] = acc[cs][ms][r] + fb[idx];
        }
      }
    }
  } else if (w < 12) {
    // ================= S waves: m-rows [16(w-8), 16(w-8)+16) =================
    const int msub = w - 8;
    const int mrow = m0 + msub * 16 + a;
    const short8 am = *(const short8*)&Ab[(size_t)mrow * 32 + g * 8];
    const float sqm = sqb[mrow];
    // prologue: tile 0 -> ldsT[0]
#pragma unroll
    for (int ns = 0; ns < 4; ++ns) {
      uint2 pk = mask_tile(Ab, sqb, 0, ns, a, g, am, sqm);
      *(uint2*)&ldsT[0][msub * 16 + a][ns * 16 + g * 4] = pk;
    }
    BAR();
    for (int tt = 0; tt < 64; ++tt) {
      if (tt < 63) {
        const int nn = (tt + 1) * 64, tb = (tt + 1) & 1;
#pragma unroll
        for (int ns = 0; ns < 4; ++ns) {
          uint2 pk = mask_tile(Ab, sqb, nn, ns, a, g, am, sqm);
          *(uint2*)&ldsT[tb][msub * 16 + a][ns * 16 + g * 4] = pk;
        }
      }
      BAR();
    }
  } else {
    // ================= STORE waves: m-rows [16(w-12), 16(w-12)+16) =================
    const int sw = w - 12;
    const int rr = lane >> 5, cc = (lane & 31) * 2;
    BAR();
    for (int tt = 0; tt < 64; ++tt) {
      const int n0 = tt * 64, buf = tt & 1;
#pragma unroll
      for (int j = 0; j < 8; ++j) {
        const int row = sw * 16 + j * 2 + rr;
        unsigned u = *(const unsigned*)&ldsT[buf][row][cc];
        f32x2 v;
        v[0] = bf2f((unsigned short)(u & 0xffff));
        v[1] = bf2f((unsigned short)(u >> 16));
        __builtin_nontemporal_store(v, (f32x2*)&maskout[(size_t)(m0 + row) * 4096 + n0 + cc]);
      }
      BAR();
    }
  }
}

extern "C" void kernel_launch(void* const* d_in, const int* in_sizes, int n_in,
                              void* d_out, int out_size, void* d_ws, size_t ws_size,
                              hipStream_t stream) {
  const float* feat  = (const float*)d_in[0];
  const float* w_red = (const float*)d_in[1];
  const float* b_red = (const float*)d_in[2];
  const float* w_val = (const float*)d_in[3];
  const float* b_val = (const float*)d_in[4];
  float* out = (float*)d_out;
  char* ws = (char*)d_ws;
  unsigned short* A   = (unsigned short*)ws;               // 1,048,576 B
  float*          sq  = (float*)        (ws + 1048576);    //    65,536 B
  unsigned short* wv  = (unsigned short*)(ws + 1114112);   //   131,072 B
  unsigned short* wr  = (unsigned short*)(ws + 1245184);   //    16,384 B
  unsigned short* val = (unsigned short*)(ws + 1261568);   // 8,388,608 B

  k_wcvt<<<dim3(288), 256, 0, stream>>>(w_val, w_red, wv, wr);
  k_prep<<<dim3(128, 4), 512, 0, stream>>>(feat, wv, wr, b_red, b_val, A, sq, val);
  k_fused<<<dim3(64, 4), 1024, 0, stream>>>(A, sq, val, feat, out);
}